// Round 7
// baseline (47889.038 us; speedup 1.0000x reference)
//
#include <hip/hip_runtime.h>
#include <cstdint>
#include <cstddef>

#define TINYF 1.17549435e-38f
#define ROWS 8

// ---------------- static device workspace ----------------
__device__ __align__(256) float g_wih0T[512 * 2048];   // [tok][gate_row]
__device__ __align__(256) float g_whh0T[512 * 2048];   // [k][gate_row]
__device__ __align__(256) float g_wih1T[512 * 2048];   // [k][gate_row]
__device__ __align__(256) float g_whh1T[512 * 2048];   // [k][gate_row]
__device__ __align__(256) float g_outwT[512 * 512];    // [k][vocab]
__device__ __align__(256) float g_pew1T[1024 * 512];   // [k][j]
__device__ __align__(256) float g_pew2T[512 * 256];    // [k][j]
__device__ __align__(256) float g_fcwT[384 * 512];     // [k][j]
__device__ __align__(256) float g_pe1[4096 * 512];
__device__ __align__(256) float g_pe2[4096 * 256];
__device__ __align__(256) float g_h0[4096 * 512];

__device__ __forceinline__ float* sel_wt(int s) {
  switch (s) {
    case 0: return g_wih0T; case 1: return g_whh0T;
    case 2: return g_wih1T; case 3: return g_whh1T;
    case 4: return g_outwT; case 5: return g_pew1T;
    case 6: return g_pew2T; case 7: return g_fcwT;
    default: return nullptr;
  }
}

// ---------------- JAX threefry2x32 (bit-exact) ----------------
__device__ __forceinline__ uint32_t rotl32(uint32_t v, int d) {
  return (v << d) | (v >> (32 - d));
}
__device__ __forceinline__ void threefry2x32(uint32_t k0, uint32_t k1,
                                             uint32_t x0, uint32_t x1,
                                             uint32_t& o0, uint32_t& o1) {
  uint32_t k2 = k0 ^ k1 ^ 0x1BD11BDAu;
#define TF_ROUND(d) { x0 += x1; x1 = rotl32(x1, (d)); x1 ^= x0; }
  x0 += k0; x1 += k1;
  TF_ROUND(13) TF_ROUND(15) TF_ROUND(26) TF_ROUND(6)
  x0 += k1; x1 += k2 + 1u;
  TF_ROUND(17) TF_ROUND(29) TF_ROUND(16) TF_ROUND(24)
  x0 += k2; x1 += k0 + 2u;
  TF_ROUND(13) TF_ROUND(15) TF_ROUND(26) TF_ROUND(6)
  x0 += k0; x1 += k1 + 3u;
  TF_ROUND(17) TF_ROUND(29) TF_ROUND(16) TF_ROUND(24)
  x0 += k1; x1 += k2 + 4u;
  TF_ROUND(13) TF_ROUND(15) TF_ROUND(26) TF_ROUND(6)
  x0 += k2; x1 += k0 + 5u;
#undef TF_ROUND
  o0 = x0; o1 = x1;
}

// partitionable random_bits (32-bit): bits = o0 ^ o1 of TF(key, (0, flat_idx));
// uniform(minval=tiny, maxval=1); gumbel = -log(-log(u)).
__device__ __forceinline__ float gumbel_from_bits(uint32_t bits) {
  float f = __uint_as_float((bits >> 9) | 0x3f800000u) - 1.0f;  // [0,1)
  float u = fmaxf(TINYF, __fadd_rn(f, TINYF));
  return -logf(-logf(u));
}

// XLA-style f32 tanh rational approx.
__device__ __forceinline__ float xla_tanh(float x) {
  float ax = fabsf(x);
  float xc = fminf(fmaxf(x, -7.90531110763549805f), 7.90531110763549805f);
  float x2 = __fmul_rn(xc, xc);
  float p = -2.76076847742355e-16f;
  p = __fadd_rn(__fmul_rn(p, x2), 2.00018790482477e-13f);
  p = __fadd_rn(__fmul_rn(p, x2), -8.60467152213735e-11f);
  p = __fadd_rn(__fmul_rn(p, x2), 5.12229709037114e-08f);
  p = __fadd_rn(__fmul_rn(p, x2), 1.48572235717979e-05f);
  p = __fadd_rn(__fmul_rn(p, x2), 6.37261928875436e-04f);
  p = __fadd_rn(__fmul_rn(p, x2), 4.89352455891786e-03f);
  p = __fmul_rn(p, xc);
  float q = 1.19825839466702e-06f;
  q = __fadd_rn(__fmul_rn(q, x2), 1.18534705686654e-04f);
  q = __fadd_rn(__fmul_rn(q, x2), 2.26843463243900e-03f);
  q = __fadd_rn(__fmul_rn(q, x2), 4.89352518554385e-03f);
  float r = __fdiv_rn(p, q);
  return (ax < 0.0004f) ? x : r;
}
__device__ __forceinline__ float xla_sigmoid(float x) {
  return __fdiv_rn(1.0f, __fadd_rn(1.0f, expf(-x)));
}

// ---------------- setup: transpose weights ----------------
// in [R][C] row-major -> out[c*R + r]
__global__ __launch_bounds__(256) void transpose_any(const float* __restrict__ in,
                                                     int R, int C, int wt_sel) {
  float* out = sel_wt(wt_sel);
  __shared__ float tile[32][33];
  const int c0 = blockIdx.x * 32, r0 = blockIdx.y * 32;
  const int tx = threadIdx.x & 31, ty = threadIdx.x >> 5;  // 32 x 8
#pragma unroll
  for (int i = 0; i < 32; i += 8)
    tile[ty + i][tx] = in[(size_t)(r0 + ty + i) * C + c0 + tx];
  __syncthreads();
#pragma unroll
  for (int i = 0; i < 32; i += 8)
    out[(size_t)(c0 + ty + i) * R + r0 + tx] = tile[tx][ty + i];
}

// ---------------- prefix: pe1, pe2, h0 ----------------
__global__ __launch_bounds__(512) void pe1_kernel(const float* __restrict__ P,
                                                  const float* __restrict__ b1) {
  __shared__ float a[1024];
  const int b = blockIdx.x, j = threadIdx.x;
  a[j] = P[(size_t)b * 1024 + j];
  a[j + 512] = P[(size_t)b * 1024 + j + 512];
  __syncthreads();
  float acc = 0.0f;
  for (int k = 0; k < 1024; ++k) acc += g_pew1T[(size_t)k * 512 + j] * a[k];
  g_pe1[(size_t)b * 512 + j] = fmaxf(__fadd_rn(acc, b1[j]), 0.0f);
}

__global__ __launch_bounds__(256) void pe2_kernel(const float* __restrict__ b2) {
  __shared__ float a[512];
  const int b = blockIdx.x, j = threadIdx.x;
  a[j] = g_pe1[(size_t)b * 512 + j];
  a[j + 256] = g_pe1[(size_t)b * 512 + j + 256];
  __syncthreads();
  float acc = 0.0f;
  for (int k = 0; k < 512; ++k) acc += g_pew2T[(size_t)k * 256 + j] * a[k];
  g_pe2[(size_t)b * 256 + j] = fmaxf(__fadd_rn(acc, b2[j]), 0.0f);
}

__global__ __launch_bounds__(512) void h0_kernel(const float* __restrict__ z,
                                                 const float* __restrict__ fcb) {
  __shared__ float a[384];
  const int b = blockIdx.x, j = threadIdx.x;
  if (j < 128) a[j] = z[(size_t)b * 128 + j];
  if (j < 256) a[128 + j] = g_pe2[(size_t)b * 256 + j];
  __syncthreads();
  float acc = 0.0f;
  for (int k = 0; k < 384; ++k) acc += g_fcwT[(size_t)k * 512 + j] * a[k];
  g_h0[(size_t)b * 512 + j] = __fadd_rn(acc, fcb[j]);
}

// ---------------- fused 100-step recurrence ----------------
// 512 blocks x 8 rows; rows fully independent -> no cross-block sync needed.
// Per block: h-state in LDS, weights streamed (register-blocked over 8 rows),
// token feedback in LDS. Semantics identical to the per-step kernel chain.
__global__ __launch_bounds__(512) void rnn_kernel(
    const float* __restrict__ bih0, const float* __restrict__ bhh0,
    const float* __restrict__ bih1, const float* __restrict__ bhh1,
    const float* __restrict__ outb, int* __restrict__ out) {
  __shared__ float sha[ROWS][512];
  __shared__ float shb[ROWS][512];
  __shared__ float sx[ROWS][512];
  __shared__ int stok[ROWS];

  const int j = threadIdx.x;
  const int b0 = blockIdx.x * ROWS;

  const float bc0i = __fadd_rn(bih0[j],        bhh0[j]);
  const float bc0g = __fadd_rn(bih0[1024 + j], bhh0[1024 + j]);
  const float bc0o = __fadd_rn(bih0[1536 + j], bhh0[1536 + j]);
  const float bc1i = __fadd_rn(bih1[j],        bhh1[j]);
  const float bc1g = __fadd_rn(bih1[1024 + j], bhh1[1024 + j]);
  const float bc1o = __fadd_rn(bih1[1536 + j], bhh1[1536 + j]);
  const float ob   = outb[j];

#pragma unroll
  for (int r = 0; r < ROWS; ++r) {
    const float h0 = g_h0[(size_t)(b0 + r) * 512 + j];
    sha[r][j] = h0;                    // h0 replicated to both LSTM layers
    shb[r][j] = h0;
  }
  if (j < ROWS) stok[j] = 511;         // x0 = one_hot(V-1)
  __syncthreads();

  for (int t = 0; t < 100; ++t) {
    uint32_t k0, k1;
    threefry2x32(0u, 1u, 0u, (uint32_t)t, k0, k1);   // keys[t] (partitionable split)

    // ---- cell0 h-term: ha @ whh0^T (gates i,g,o; f dead) ----
    float ai[ROWS], ag[ROWS], ao[ROWS];
#pragma unroll
    for (int r = 0; r < ROWS; ++r) { ai[r] = 0.0f; ag[r] = 0.0f; ao[r] = 0.0f; }
#pragma unroll 4
    for (int k = 0; k < 512; ++k) {
      const float* wr = g_whh0T + (size_t)k * 2048;
      const float wi = wr[j], wg = wr[1024 + j], wo = wr[1536 + j];
#pragma unroll
      for (int r = 0; r < ROWS; ++r) {
        const float hv = sha[r][k];
        ai[r] += wi * hv; ag[r] += wg * hv; ao[r] += wo * hv;
      }
    }
    __syncthreads();                    // all reads of sha complete
#pragma unroll
    for (int r = 0; r < ROWS; ++r) {
      const float* xr = g_wih0T + (size_t)stok[r] * 2048;  // exact one-hot x-term
      const float iv = __fadd_rn(__fadd_rn(xr[j],        ai[r]), bc0i);
      const float gv = __fadd_rn(__fadd_rn(xr[1024 + j], ag[r]), bc0g);
      const float ov = __fadd_rn(__fadd_rn(xr[1536 + j], ao[r]), bc0o);
      const float c = __fmul_rn(xla_sigmoid(iv), xla_tanh(gv));
      sha[r][j] = __fmul_rn(xla_sigmoid(ov), xla_tanh(c));
    }
    __syncthreads();                    // sha now holds ha'

    // ---- cell1: ha' @ wih1^T + hb @ whh1^T ----
    float xi[ROWS], xg[ROWS], xo[ROWS], hi[ROWS], hg[ROWS], ho[ROWS];
#pragma unroll
    for (int r = 0; r < ROWS; ++r) {
      xi[r] = 0.0f; xg[r] = 0.0f; xo[r] = 0.0f;
      hi[r] = 0.0f; hg[r] = 0.0f; ho[r] = 0.0f;
    }
#pragma unroll 2
    for (int k = 0; k < 512; ++k) {
      const float* wx = g_wih1T + (size_t)k * 2048;
      const float* wh = g_whh1T + (size_t)k * 2048;
      const float wxi = wx[j], wxg = wx[1024 + j], wxo = wx[1536 + j];
      const float whi = wh[j], whg = wh[1024 + j], who = wh[1536 + j];
#pragma unroll
      for (int r = 0; r < ROWS; ++r) {
        const float xv = sha[r][k], hv = shb[r][k];
        xi[r] += wxi * xv; xg[r] += wxg * xv; xo[r] += wxo * xv;
        hi[r] += whi * hv; hg[r] += whg * hv; ho[r] += who * hv;
      }
    }
    __syncthreads();                    // all reads of shb complete
#pragma unroll
    for (int r = 0; r < ROWS; ++r) {
      const float iv = __fadd_rn(__fadd_rn(xi[r], hi[r]), bc1i);
      const float gv = __fadd_rn(__fadd_rn(xg[r], hg[r]), bc1g);
      const float ov = __fadd_rn(__fadd_rn(xo[r], ho[r]), bc1o);
      const float c = __fmul_rn(xla_sigmoid(iv), xla_tanh(gv));
      shb[r][j] = __fmul_rn(xla_sigmoid(ov), xla_tanh(c));
    }
    __syncthreads();                    // shb now holds hb'

    // ---- logits + gumbel ----
    float lg[ROWS];
#pragma unroll
    for (int r = 0; r < ROWS; ++r) lg[r] = 0.0f;
#pragma unroll 4
    for (int k = 0; k < 512; ++k) {
      const float w = g_outwT[(size_t)k * 512 + j];
#pragma unroll
      for (int r = 0; r < ROWS; ++r) lg[r] += w * shb[r][k];
    }
#pragma unroll
    for (int r = 0; r < ROWS; ++r) {
      const uint32_t cnt = (uint32_t)((b0 + r) * 512 + j);   // flat idx in [B,V]
      uint32_t o0, o1;
      threefry2x32(k0, k1, 0u, cnt, o0, o1);
      sx[r][j] = __fadd_rn(gumbel_from_bits(o0 ^ o1), __fadd_rn(lg[r], ob));
    }
    __syncthreads();

    // ---- per-row argmax (wave w -> row w), first-index tiebreak ----
    {
      const int r = j >> 6, lane = j & 63;
      float bv = -3.402823466e38f;
      int bi = 0;
#pragma unroll
      for (int i = 0; i < 8; ++i) {
        const int v = i * 64 + lane;
        const float x = sx[r][v];
        if (x > bv) { bv = x; bi = v; }     // strict >: earliest v wins per lane
      }
#pragma unroll
      for (int d = 1; d < 64; d <<= 1) {
        const float ov = __shfl_xor(bv, d, 64);
        const int oi = __shfl_xor(bi, d, 64);
        if (ov > bv || (ov == bv && oi < bi)) { bv = ov; bi = oi; }
      }
      if (lane == 0) {
        bi = bi < 0 ? 0 : (bi > 511 ? 511 : bi);
        stok[r] = bi;
        out[(size_t)(b0 + r) * 100 + t] = bi;
      }
    }
    __syncthreads();
  }
}

// ---------------- host launcher ----------------
extern "C" void kernel_launch(void* const* d_in, const int* in_sizes, int n_in,
                              void* d_out, int out_size, void* d_ws, size_t ws_size,
                              hipStream_t stream) {
  (void)in_sizes; (void)n_in; (void)out_size; (void)d_ws; (void)ws_size;
  const float* P     = (const float*)d_in[0];
  const float* z     = (const float*)d_in[1];
  const float* pe_w1 = (const float*)d_in[2];
  const float* pe_b1 = (const float*)d_in[3];
  const float* pe_w2 = (const float*)d_in[4];
  const float* pe_b2 = (const float*)d_in[5];
  const float* fc_w  = (const float*)d_in[6];
  const float* fc_b  = (const float*)d_in[7];
  const float* wih0  = (const float*)d_in[8];
  const float* whh0  = (const float*)d_in[9];
  const float* bih0  = (const float*)d_in[10];
  const float* bhh0  = (const float*)d_in[11];
  const float* wih1  = (const float*)d_in[12];
  const float* whh1  = (const float*)d_in[13];
  const float* bih1  = (const float*)d_in[14];
  const float* bhh1  = (const float*)d_in[15];
  const float* out_w = (const float*)d_in[16];
  const float* out_b = (const float*)d_in[17];
  int* out = (int*)d_out;

  transpose_any<<<dim3(16, 64), 256, 0, stream>>>(wih0, 2048, 512, 0);
  transpose_any<<<dim3(16, 64), 256, 0, stream>>>(whh0, 2048, 512, 1);
  transpose_any<<<dim3(16, 64), 256, 0, stream>>>(wih1, 2048, 512, 2);
  transpose_any<<<dim3(16, 64), 256, 0, stream>>>(whh1, 2048, 512, 3);
  transpose_any<<<dim3(16, 16), 256, 0, stream>>>(out_w, 512, 512, 4);
  transpose_any<<<dim3(32, 16), 256, 0, stream>>>(pe_w1, 512, 1024, 5);
  transpose_any<<<dim3(16, 8),  256, 0, stream>>>(pe_w2, 256, 512, 6);
  transpose_any<<<dim3(12, 16), 256, 0, stream>>>(fc_w, 512, 384, 7);

  pe1_kernel<<<4096, 512, 0, stream>>>(P, pe_b1);
  pe2_kernel<<<4096, 256, 0, stream>>>(pe_b2);
  h0_kernel<<<4096, 512, 0, stream>>>(z, fc_b);

  rnn_kernel<<<512, 512, 0, stream>>>(bih0, bhh0, bih1, bhh1, out_b, out);
}